// Round 10
// baseline (478.012 us; speedup 1.0000x reference)
//
#include <hip/hip_runtime.h>
#include <hip/hip_bf16.h>

#define NN 8192
#define FIN 256
#define FO 128
#define WCH 1024                // cols per wave (8 waves cover 8192)
#define WSTEP 16                // 64-col steps per wave
#define L2E 1.4426950408889634f
#define C2  0.28853900817779268f   // 0.2 * log2(e)

typedef __bf16 bf16x8 __attribute__((ext_vector_type(8)));
typedef __bf16 bf16x2 __attribute__((ext_vector_type(2)));
typedef float  f32x4  __attribute__((ext_vector_type(4)));

// ---------------------------------------------------------------------------
// Kernel 1: h = x@W (fp32 accum), write Bpack (bf16 MFMA-B-fragment layout),
//           f_src (fp32), and G1/G2 = exp2(f_dst*log2e), exp2(f_dst*0.2*log2e).
// Bpack element (kg, nt, lane=q*16+m, t) = h[j = kg*32+q*8+t][n = nt*16+m]
// ---------------------------------------------------------------------------
__global__ __launch_bounds__(256) void k_proj(
    const float* __restrict__ x, const float* __restrict__ W,
    const float* __restrict__ a_src, const float* __restrict__ a_dst,
    __bf16* __restrict__ Bp, float* __restrict__ f_src,
    float* __restrict__ g1, float* __restrict__ g2)
{
  __shared__ float xs[16 * FIN];     // 16 KB x-tile
  __shared__ float fs[16], fd[16];
  const int tid = threadIdx.x;
  const int i0 = blockIdx.x * 16;

  const float4* xg = (const float4*)(x + (size_t)i0 * FIN);
  float4* xs4 = (float4*)xs;
  #pragma unroll
  for (int t = 0; t < 4; t++) xs4[tid + 256 * t] = xg[tid + 256 * t];
  if (tid < 16) { fs[tid] = 0.f; fd[tid] = 0.f; }
  __syncthreads();

  const int cq = tid & 31;    // column quad: cols c0..c0+3
  const int rg = tid >> 5;    // row group: rows r0, r0+1
  const int c0 = cq * 4;
  const int r0 = rg * 2;
  float acc0[4] = {0.f,0.f,0.f,0.f};
  float acc1[4] = {0.f,0.f,0.f,0.f};
  const float* xr0 = xs + r0 * FIN;
  const float* xr1 = xs + (r0 + 1) * FIN;

  for (int k = 0; k < FIN; k += 4) {
    float4 xa = *(const float4*)(xr0 + k);
    float4 xb = *(const float4*)(xr1 + k);
    #pragma unroll
    for (int kk = 0; kk < 4; kk++) {
      float4 wv = *(const float4*)(W + (size_t)(k + kk) * FO + c0);
      float xav = ((const float*)&xa)[kk];
      float xbv = ((const float*)&xb)[kk];
      acc0[0] += xav * wv.x; acc0[1] += xav * wv.y;
      acc0[2] += xav * wv.z; acc0[3] += xav * wv.w;
      acc1[0] += xbv * wv.x; acc1[1] += xbv * wv.y;
      acc1[2] += xbv * wv.z; acc1[3] += xbv * wv.w;
    }
  }

  float4 as = *(const float4*)(a_src + c0);
  float4 ad = *(const float4*)(a_dst + c0);
  float ps0 = acc0[0]*as.x + acc0[1]*as.y + acc0[2]*as.z + acc0[3]*as.w;
  float ps1 = acc1[0]*as.x + acc1[1]*as.y + acc1[2]*as.z + acc1[3]*as.w;
  float pd0 = acc0[0]*ad.x + acc0[1]*ad.y + acc0[2]*ad.z + acc0[3]*ad.w;
  float pd1 = acc1[0]*ad.x + acc1[1]*ad.y + acc1[2]*ad.z + acc1[3]*ad.w;
  atomicAdd(&fs[r0],     ps0);
  atomicAdd(&fs[r0 + 1], ps1);
  atomicAdd(&fd[r0],     pd0);
  atomicAdd(&fd[r0 + 1], pd1);

  const int j0 = i0 + r0;
  const int kg = j0 >> 5;
  const int q  = (j0 >> 3) & 3;
  const int t0 = j0 & 7;
  #pragma unroll
  for (int c = 0; c < 4; c++) {
    const int n = c0 + c;
    bf16x2 v;
    v[0] = (__bf16)acc0[c];
    v[1] = (__bf16)acc1[c];
    size_t idx = ((size_t)(kg * 8 + (n >> 4)) * 64 + q * 16 + (n & 15)) * 8 + t0;
    *(bf16x2*)(Bp + idx) = v;
  }
  __syncthreads();
  if (tid < 16) {
    float d = fd[tid];
    f_src[i0 + tid] = fs[tid];
    g1[i0 + tid] = __builtin_amdgcn_exp2f(d * L2E);
    g2[i0 + tid] = __builtin_amdgcn_exp2f(d * C2);
  }
}

// ---------------------------------------------------------------------------
// Kernel 2: streaming P@H, L1-transaction-minimized.
// 256 blocks x 512 thr (8 waves). Block owns 32 rows x all 8192 cols; wave w
// handles cols [w*1024, +1024) for BOTH 16-row m-tiles (each B-frag feeds 2
// MFMAs -> Bp traffic halved to 512 MB). G1/G2 staged in LDS (broadcast
// ds_reads, off the L1 path). adj loads NON-TEMPORAL (bypass L1; ext_vector
// f32x4 type — clang rejects HIP_vector_type here). Depth-2 register dbuf on
// adj; no loop barriers; LDS-merge epilogue; no global atomics.
// Separable softmax: p = adj ? max(F1_i*G1_j, F2_i*G2_j) : 0.
// ---------------------------------------------------------------------------
__global__ __launch_bounds__(512, 2) void k_attn(
    const float* __restrict__ adj, const __bf16* __restrict__ Bp,
    const float* __restrict__ f_src, const float* __restrict__ g1,
    const float* __restrict__ g2, float* __restrict__ out)
{
  __shared__ float G1s[NN];            // 32 KB
  __shared__ float G2s[NN];            // 32 KB
  __shared__ float accbuf[32 * FO];    // 16 KB (1024 float4)
  __shared__ float lred[32];
  const int tid = threadIdx.x;
  const int i0 = blockIdx.x * 32;

  // stage G1/G2 into LDS (coalesced float4) + zero merge buffers
  {
    const float4* s1 = (const float4*)g1;
    const float4* s2 = (const float4*)g2;
    float4* d1 = (float4*)G1s;
    float4* d2 = (float4*)G2s;
    #pragma unroll
    for (int t = 0; t < 4; t++) {
      d1[tid + 512 * t] = s1[tid + 512 * t];
      d2[tid + 512 * t] = s2[tid + 512 * t];
    }
  }
  ((float4*)accbuf)[tid]       = (float4){0.f, 0.f, 0.f, 0.f};
  ((float4*)accbuf)[tid + 512] = (float4){0.f, 0.f, 0.f, 0.f};
  if (tid < 32) lred[tid] = 0.f;

  const int w = tid >> 6;       // wave = k-split index (0..7)
  const int lane = tid & 63;
  const int m = lane & 15;
  const int q = lane >> 4;
  const int jbase = w * WCH;

  float F1[2], F2[2];
  #pragma unroll
  for (int mt = 0; mt < 2; mt++) {
    float s = f_src[i0 + mt * 16 + m];
    F1[mt] = __builtin_amdgcn_exp2f(s * L2E);
    F2[mt] = __builtin_amdgcn_exp2f(s * C2);
  }

  f32x4 acc[2][8];
  #pragma unroll
  for (int mt = 0; mt < 2; mt++)
    #pragma unroll
    for (int nt = 0; nt < 8; nt++) acc[mt][nt] = (f32x4){0.f, 0.f, 0.f, 0.f};
  float psum[2] = {0.f, 0.f};

  const float* adjp[2];
  adjp[0] = adj + (size_t)(i0 + m) * NN + jbase + q * 8;
  adjp[1] = adjp[0] + (size_t)16 * NN;
  const __bf16* bb = Bp + (size_t)(jbase >> 5) * 4096 + lane * 8;

  __syncthreads();   // G-stage + accbuf zero visible

  // depth-2 dbuf: c[mt][g][0/1] = 8 f32x4, non-temporal (L1 bypass)
  f32x4 c[2][2][2];
  #pragma unroll
  for (int mt = 0; mt < 2; mt++) {
    c[mt][0][0] = __builtin_nontemporal_load((const f32x4*)(adjp[mt] + 0));
    c[mt][0][1] = __builtin_nontemporal_load((const f32x4*)(adjp[mt] + 4));
    c[mt][1][0] = __builtin_nontemporal_load((const f32x4*)(adjp[mt] + 32));
    c[mt][1][1] = __builtin_nontemporal_load((const f32x4*)(adjp[mt] + 36));
  }

  for (int st = 0; st < WSTEP; ++st) {
    f32x4 n[2][2][2];
    if (st < WSTEP - 1) {
      #pragma unroll
      for (int mt = 0; mt < 2; mt++) {
        const float* ap = adjp[mt] + (st + 1) * 64;
        n[mt][0][0] = __builtin_nontemporal_load((const f32x4*)(ap + 0));
        n[mt][0][1] = __builtin_nontemporal_load((const f32x4*)(ap + 4));
        n[mt][1][0] = __builtin_nontemporal_load((const f32x4*)(ap + 32));
        n[mt][1][1] = __builtin_nontemporal_load((const f32x4*)(ap + 36));
      }
    }
    #pragma unroll
    for (int g = 0; g < 2; ++g) {
      const int jj = jbase + st * 64 + g * 32 + q * 8;
      float4 u0 = *(const float4*)(G1s + jj);
      float4 u1 = *(const float4*)(G1s + jj + 4);
      float4 v0 = *(const float4*)(G2s + jj);
      float4 v1 = *(const float4*)(G2s + jj + 4);

      bf16x8 af[2];
      #pragma unroll
      for (int mt = 0; mt < 2; mt++) {
        f32x4 a0 = c[mt][g][0];
        f32x4 a1 = c[mt][g][1];
        const float f1 = F1[mt], f2 = F2[mt];
        float p0 = (a0.x > 0.f) ? fmaxf(f1 * u0.x, f2 * v0.x) : 0.f;
        float p1 = (a0.y > 0.f) ? fmaxf(f1 * u0.y, f2 * v0.y) : 0.f;
        float p2 = (a0.z > 0.f) ? fmaxf(f1 * u0.z, f2 * v0.z) : 0.f;
        float p3 = (a0.w > 0.f) ? fmaxf(f1 * u0.w, f2 * v0.w) : 0.f;
        float p4 = (a1.x > 0.f) ? fmaxf(f1 * u1.x, f2 * v1.x) : 0.f;
        float p5 = (a1.y > 0.f) ? fmaxf(f1 * u1.y, f2 * v1.y) : 0.f;
        float p6 = (a1.z > 0.f) ? fmaxf(f1 * u1.z, f2 * v1.z) : 0.f;
        float p7 = (a1.w > 0.f) ? fmaxf(f1 * u1.w, f2 * v1.w) : 0.f;
        psum[mt] += ((p0 + p1) + (p2 + p3)) + ((p4 + p5) + (p6 + p7));
        bf16x8 a;
        a[0] = (__bf16)p0; a[1] = (__bf16)p1; a[2] = (__bf16)p2; a[3] = (__bf16)p3;
        a[4] = (__bf16)p4; a[5] = (__bf16)p5; a[6] = (__bf16)p6; a[7] = (__bf16)p7;
        af[mt] = a;
      }

      const __bf16* bs = bb + (size_t)(st * 2 + g) * 4096;
      #pragma unroll
      for (int nt = 0; nt < 8; nt++) {
        bf16x8 bfrag = *(const bf16x8*)(bs + nt * 512);
        acc[0][nt] = __builtin_amdgcn_mfma_f32_16x16x32_bf16(af[0], bfrag, acc[0][nt], 0, 0, 0);
        acc[1][nt] = __builtin_amdgcn_mfma_f32_16x16x32_bf16(af[1], bfrag, acc[1][nt], 0, 0, 0);
      }
    }
    if (st < WSTEP - 1) {
      #pragma unroll
      for (int mt = 0; mt < 2; mt++)
        #pragma unroll
        for (int g = 0; g < 2; g++) {
          c[mt][g][0] = n[mt][g][0];
          c[mt][g][1] = n[mt][g][1];
        }
    }
  }

  // denominator partials: rows keyed by m live in lanes {m, m+16, m+32, m+48}
  #pragma unroll
  for (int mt = 0; mt < 2; mt++) {
    float p = psum[mt];
    p += __shfl_xor(p, 16);
    p += __shfl_xor(p, 32);
    if (lane < 16) atomicAdd(&lred[mt * 16 + lane], p);
  }

  // numerator partial merge in LDS (C/D: row=q*4+r, col=nt*16+m)
  #pragma unroll
  for (int mt = 0; mt < 2; mt++) {
    #pragma unroll
    for (int nt = 0; nt < 8; nt++) {
      #pragma unroll
      for (int r = 0; r < 4; r++) {
        atomicAdd(&accbuf[(mt * 16 + q * 4 + r) * FO + nt * 16 + m], acc[mt][nt][r]);
      }
    }
  }
  __syncthreads();

  // fused divide + coalesced store: 1024 float4 = 32 rows x 128 cols
  #pragma unroll
  for (int t = 0; t < 2; t++) {
    const int idx = tid + t * 512;
    const float inv = 1.0f / lred[idx >> 5];
    float4 v = ((const float4*)accbuf)[idx];
    float4 o;
    o.x = v.x * inv; o.y = v.y * inv; o.z = v.z * inv; o.w = v.w * inv;
    ((float4*)(out + (size_t)i0 * FO))[idx] = o;
  }
}

extern "C" void kernel_launch(void* const* d_in, const int* in_sizes, int n_in,
                              void* d_out, int out_size, void* d_ws, size_t ws_size,
                              hipStream_t stream) {
  const float* x     = (const float*)d_in[0];
  const float* adj   = (const float*)d_in[1];
  const float* W     = (const float*)d_in[2];
  const float* a_src = (const float*)d_in[3];
  const float* a_dst = (const float*)d_in[4];
  float* out = (float*)d_out;

  char* ws = (char*)d_ws;
  __bf16* Bp   = (__bf16*)ws;                                  // 2 MB
  float* f_src = (float*)(ws + 2097152);                       // 32 KB
  float* g1    = (float*)(ws + 2097152 + 32768);               // 32 KB
  float* g2    = (float*)(ws + 2097152 + 65536);               // 32 KB

  hipLaunchKernelGGL(k_proj, dim3(512), dim3(256), 0, stream,
                     x, W, a_src, a_dst, Bp, f_src, g1, g2);
  hipLaunchKernelGGL(k_attn, dim3(256), dim3(512), 0, stream,
                     adj, Bp, f_src, g1, g2, out);
}